// Round 4
// baseline (104.004 us; speedup 1.0000x reference)
//
#include <hip/hip_runtime.h>

#define CONVEX_WEIGHT 0.1f

// Native clang vector type — __builtin_nontemporal_load requires a real
// vector type, not HIP's HIP_vector_type class.
typedef float floatx4 __attribute__((ext_vector_type(4)));

// Branchless compare-exchange on (ax,ay),(bx,by) by angle = atan2(y,x) in (-pi,pi].
// atan2 < 0 <=> y < 0. Same half-plane: span < pi, so cross(a,b)>0 <=> ang(a)<ang(b).
// All selects -> v_cndmask, no control flow, no address-taken arrays (SROA-safe).
#define ANG_CE(ax, ay, bx, by)                                            \
    {                                                                     \
        bool ha = (ay) < 0.0f;                                            \
        bool hb = (by) < 0.0f;                                            \
        float cr_ = (ax) * (by) - (ay) * (bx);                            \
        bool a_first = (ha == hb) ? (cr_ > 0.0f) : ha;                    \
        float t;                                                          \
        t = a_first ? (ax) : (bx); (bx) = a_first ? (bx) : (ax); (ax) = t;\
        t = a_first ? (ay) : (by); (by) = a_first ? (by) : (ay); (ay) = t;\
    }

__global__ __launch_bounds__(256) void mgiou2dplus_kernel(
    const floatx4* __restrict__ pred4,
    const floatx4* __restrict__ targ4,
    float* __restrict__ out,
    int B)
{
    int b = blockIdx.x * blockDim.x + threadIdx.x;
    if (b >= B) return;

    // ---- issue all 4 loads up front (non-temporal: pure streaming data) ----
    floatx4 pa = __builtin_nontemporal_load(&pred4[2 * b]);
    floatx4 pb = __builtin_nontemporal_load(&pred4[2 * b + 1]);
    floatx4 ta = __builtin_nontemporal_load(&targ4[2 * b]);
    floatx4 tb = __builtin_nontemporal_load(&targ4[2 * b + 1]);

    float px0 = pa.x, py0 = pa.y, px1 = pa.z, py1 = pa.w;
    float px2 = pb.x, py2 = pb.y, px3 = pb.z, py3 = pb.w;
    float tx0 = ta.x, ty0 = ta.y, tx1 = ta.z, ty1 = ta.w;
    float tx2 = tb.x, ty2 = tb.y, tx3 = tb.z, ty3 = tb.w;

    // ---- centers, centered coords ----
    float pcx = (px0 + px1 + px2 + px3) * 0.25f;
    float pcy = (py0 + py1 + py2 + py3) * 0.25f;
    float tcx = (tx0 + tx1 + tx2 + tx3) * 0.25f;
    float tcy = (ty0 + ty1 + ty2 + ty3) * 0.25f;

    float a0x = px0 - pcx, a0y = py0 - pcy;
    float a1x = px1 - pcx, a1y = py1 - pcy;
    float a2x = px2 - pcx, a2y = py2 - pcy;
    float a3x = px3 - pcx, a3y = py3 - pcy;

    float b0x = tx0 - tcx, b0y = ty0 - tcy;
    float b1x = tx1 - tcx, b1y = ty1 - tcy;
    float b2x = tx2 - tcx, b2y = ty2 - tcy;
    float b3x = tx3 - tcx, b3y = ty3 - tcy;

    // ---- 5-CE sorting network, ascending by angle (branchless) ----
    ANG_CE(a0x, a0y, a1x, a1y) ANG_CE(a2x, a2y, a3x, a3y)
    ANG_CE(a0x, a0y, a2x, a2y) ANG_CE(a1x, a1y, a3x, a3y)
    ANG_CE(a1x, a1y, a2x, a2y)

    ANG_CE(b0x, b0y, b1x, b1y) ANG_CE(b2x, b2y, b3x, b3y)
    ANG_CE(b0x, b0y, b2x, b2y) ANG_CE(b1x, b1y, b3x, b3y)
    ANG_CE(b1x, b1y, b2x, b2y)

    // ---- per-axis 1D GIoU; axis = normal(edge) = (ey, -ex) ----
    // Balanced min/max trees (depth 2) for ILP; one divide per axis.
    float gsum = 0.0f;

#define AXIS_GIOU(nx, ny)                                                  \
    {                                                                      \
        float nx_ = (nx), ny_ = (ny);                                      \
        float q0 = px0 * nx_ + py0 * ny_;                                  \
        float q1 = px1 * nx_ + py1 * ny_;                                  \
        float q2 = px2 * nx_ + py2 * ny_;                                  \
        float q3 = px3 * nx_ + py3 * ny_;                                  \
        float r0 = tx0 * nx_ + ty0 * ny_;                                  \
        float r1 = tx1 * nx_ + ty1 * ny_;                                  \
        float r2 = tx2 * nx_ + ty2 * ny_;                                  \
        float r3 = tx3 * nx_ + ty3 * ny_;                                  \
        float mn1 = fminf(fminf(q0, q1), fminf(q2, q3));                   \
        float mx1 = fmaxf(fmaxf(q0, q1), fmaxf(q2, q3));                   \
        float mn2 = fminf(fminf(r0, r1), fminf(r2, r3));                   \
        float mx2 = fmaxf(fmaxf(r0, r1), fmaxf(r2, r3));                   \
        float inter = fmaxf(fminf(mx1, mx2) - fmaxf(mn1, mn2), 0.0f);      \
        float uni   = (mx1 - mn1) + (mx2 - mn2) - inter;                   \
        float hull  = fmaxf(mx1, mx2) - fminf(mn1, mn2);                   \
        /* inter/uni - (hull-uni)/hull == (inter*hull - (hull-uni)*uni)/(uni*hull) */ \
        gsum += __fdividef(inter * hull - (hull - uni) * uni, uni * hull); \
    }

    AXIS_GIOU(a1y - a0y, a0x - a1x)
    AXIS_GIOU(a2y - a1y, a1x - a2x)
    AXIS_GIOU(a3y - a2y, a2x - a3x)
    AXIS_GIOU(a0y - a3y, a3x - a0x)
    AXIS_GIOU(b1y - b0y, b0x - b1x)
    AXIS_GIOU(b2y - b1y, b1x - b2x)
    AXIS_GIOU(b3y - b2y, b2x - b3x)
    AXIS_GIOU(b0y - b3y, b3x - b0x)
#undef AXIS_GIOU

    float loss = (1.0f - gsum * 0.125f) * 0.5f;

    // ---- convexity penalty on pred (original vertex order) ----
    float c0, c1, c2, c3;
    {
        float e1x, e1y, e2x, e2y;
        e1x = px3 - px0; e1y = py3 - py0; e2x = px1 - px0; e2y = py1 - py0;
        c0 = e1x * e2y - e1y * e2x;
        e1x = px0 - px1; e1y = py0 - py1; e2x = px2 - px1; e2y = py2 - py1;
        c1 = e1x * e2y - e1y * e2x;
        e1x = px1 - px2; e1y = py1 - py2; e2x = px3 - px2; e2y = py3 - py2;
        c2 = e1x * e2y - e1y * e2x;
        e1x = px2 - px3; e1y = py2 - py3; e2x = px0 - px3; e2y = py0 - py3;
        c3 = e1x * e2y - e1y * e2x;
    }
    float sref = (c0 < 0.0f) ? -1.0f : 1.0f;   // sign(c0), 0 -> +1
    float pen = fmaxf(-sref * c0, 0.0f) + fmaxf(-sref * c1, 0.0f)
              + fmaxf(-sref * c2, 0.0f) + fmaxf(-sref * c3, 0.0f);

    loss += CONVEX_WEIGHT * (pen * 0.25f);

    __builtin_nontemporal_store(loss, &out[b]);
}

extern "C" void kernel_launch(void* const* d_in, const int* in_sizes, int n_in,
                              void* d_out, int out_size, void* d_ws, size_t ws_size,
                              hipStream_t stream)
{
    const floatx4* pred = (const floatx4*)d_in[0];
    const floatx4* targ = (const floatx4*)d_in[1];
    float* out = (float*)d_out;
    int B = in_sizes[0] / 8;   // (B, 4, 2) floats

    const int threads = 256;
    int blocks = (B + threads - 1) / threads;
    mgiou2dplus_kernel<<<blocks, threads, 0, stream>>>(pred, targ, out, B);
}

// Round 5
// 95.608 us; speedup vs baseline: 1.0878x; 1.0878x over previous
//
#include <hip/hip_runtime.h>

#define CONVEX_WEIGHT 0.1f

// Branchless compare-exchange on (ax,ay),(bx,by) by angle = atan2(y,x) in (-pi,pi].
// atan2 < 0 <=> y < 0. Same half-plane: span < pi, so cross(a,b)>0 <=> ang(a)<ang(b).
// All selects -> v_cndmask, no control flow, no address-taken arrays (SROA-safe).
#define ANG_CE(ax, ay, bx, by)                                            \
    {                                                                     \
        bool ha = (ay) < 0.0f;                                            \
        bool hb = (by) < 0.0f;                                            \
        float cr_ = (ax) * (by) - (ay) * (bx);                            \
        bool a_first = (ha == hb) ? (cr_ > 0.0f) : ha;                    \
        float t;                                                          \
        t = a_first ? (ax) : (bx); (bx) = a_first ? (bx) : (ax); (ax) = t;\
        t = a_first ? (ay) : (by); (by) = a_first ? (by) : (ay); (ay) = t;\
    }

__global__ __launch_bounds__(256) void mgiou2dplus_kernel(
    const float4* __restrict__ pred4,
    const float4* __restrict__ targ4,
    float* __restrict__ out,
    int B)
{
    int b = blockIdx.x * blockDim.x + threadIdx.x;
    if (b >= B) return;

    // ---- plain cached loads: inputs were just d2d-restored, so they sit in
    // L3 (256 MB >> 64 MB of inputs); nt hints would forfeit those hits ----
    float4 pa = pred4[2 * b];
    float4 pb = pred4[2 * b + 1];
    float4 ta = targ4[2 * b];
    float4 tb = targ4[2 * b + 1];

    float px0 = pa.x, py0 = pa.y, px1 = pa.z, py1 = pa.w;
    float px2 = pb.x, py2 = pb.y, px3 = pb.z, py3 = pb.w;
    float tx0 = ta.x, ty0 = ta.y, tx1 = ta.z, ty1 = ta.w;
    float tx2 = tb.x, ty2 = tb.y, tx3 = tb.z, ty3 = tb.w;

    // ---- centers, centered coords ----
    float pcx = (px0 + px1 + px2 + px3) * 0.25f;
    float pcy = (py0 + py1 + py2 + py3) * 0.25f;
    float tcx = (tx0 + tx1 + tx2 + tx3) * 0.25f;
    float tcy = (ty0 + ty1 + ty2 + ty3) * 0.25f;

    float a0x = px0 - pcx, a0y = py0 - pcy;
    float a1x = px1 - pcx, a1y = py1 - pcy;
    float a2x = px2 - pcx, a2y = py2 - pcy;
    float a3x = px3 - pcx, a3y = py3 - pcy;

    float b0x = tx0 - tcx, b0y = ty0 - tcy;
    float b1x = tx1 - tcx, b1y = ty1 - tcy;
    float b2x = tx2 - tcx, b2y = ty2 - tcy;
    float b3x = tx3 - tcx, b3y = ty3 - tcy;

    // ---- 5-CE sorting network, ascending by angle (branchless) ----
    ANG_CE(a0x, a0y, a1x, a1y) ANG_CE(a2x, a2y, a3x, a3y)
    ANG_CE(a0x, a0y, a2x, a2y) ANG_CE(a1x, a1y, a3x, a3y)
    ANG_CE(a1x, a1y, a2x, a2y)

    ANG_CE(b0x, b0y, b1x, b1y) ANG_CE(b2x, b2y, b3x, b3y)
    ANG_CE(b0x, b0y, b2x, b2y) ANG_CE(b1x, b1y, b3x, b3y)
    ANG_CE(b1x, b1y, b2x, b2y)

    // ---- per-axis 1D GIoU; axis = normal(edge) = (ey, -ex) ----
    // Balanced min/max trees (depth 2) for ILP. Per-axis giou is kept as a
    // fraction (num, den); fractions are combined pairwise so the whole
    // 8-axis sum costs ONE reciprocal instead of eight.
    //   giou = inter/uni - (hull-uni)/hull = (inter*hull - (hull-uni)*uni)/(uni*hull)
    float num[8], den[8];
    int axi = 0;

#define AXIS_GIOU(nx, ny)                                                  \
    {                                                                      \
        float nx_ = (nx), ny_ = (ny);                                      \
        float q0 = px0 * nx_ + py0 * ny_;                                  \
        float q1 = px1 * nx_ + py1 * ny_;                                  \
        float q2 = px2 * nx_ + py2 * ny_;                                  \
        float q3 = px3 * nx_ + py3 * ny_;                                  \
        float r0 = tx0 * nx_ + ty0 * ny_;                                  \
        float r1 = tx1 * nx_ + ty1 * ny_;                                  \
        float r2 = tx2 * nx_ + ty2 * ny_;                                  \
        float r3 = tx3 * nx_ + ty3 * ny_;                                  \
        float mn1 = fminf(fminf(q0, q1), fminf(q2, q3));                   \
        float mx1 = fmaxf(fmaxf(q0, q1), fmaxf(q2, q3));                   \
        float mn2 = fminf(fminf(r0, r1), fminf(r2, r3));                   \
        float mx2 = fmaxf(fmaxf(r0, r1), fmaxf(r2, r3));                   \
        float inter = fmaxf(fminf(mx1, mx2) - fmaxf(mn1, mn2), 0.0f);      \
        float uni   = (mx1 - mn1) + (mx2 - mn2) - inter;                   \
        float hull  = fmaxf(mx1, mx2) - fminf(mn1, mn2);                   \
        num[axi] = inter * hull - (hull - uni) * uni;                      \
        den[axi] = uni * hull;                                             \
        ++axi;                                                             \
    }

    AXIS_GIOU(a1y - a0y, a0x - a1x)
    AXIS_GIOU(a2y - a1y, a1x - a2x)
    AXIS_GIOU(a3y - a2y, a2x - a3x)
    AXIS_GIOU(a0y - a3y, a3x - a0x)
    AXIS_GIOU(b1y - b0y, b0x - b1x)
    AXIS_GIOU(b2y - b1y, b1x - b2x)
    AXIS_GIOU(b3y - b2y, b2x - b3x)
    AXIS_GIOU(b0y - b3y, b3x - b0x)
#undef AXIS_GIOU

    // Pairwise fraction combine: 7 combines, then a single fast divide.
    float n01 = num[0] * den[1] + num[1] * den[0], d01 = den[0] * den[1];
    float n23 = num[2] * den[3] + num[3] * den[2], d23 = den[2] * den[3];
    float n45 = num[4] * den[5] + num[5] * den[4], d45 = den[4] * den[5];
    float n67 = num[6] * den[7] + num[7] * den[6], d67 = den[6] * den[7];
    float n03 = n01 * d23 + n23 * d01, d03 = d01 * d23;
    float n47 = n45 * d67 + n67 * d45, d47 = d45 * d67;
    float nall = n03 * d47 + n47 * d03, dall = d03 * d47;
    float gsum = __fdividef(nall, dall);

    float loss = (1.0f - gsum * 0.125f) * 0.5f;

    // ---- convexity penalty on pred (original vertex order) ----
    float c0, c1, c2, c3;
    {
        float e1x, e1y, e2x, e2y;
        e1x = px3 - px0; e1y = py3 - py0; e2x = px1 - px0; e2y = py1 - py0;
        c0 = e1x * e2y - e1y * e2x;
        e1x = px0 - px1; e1y = py0 - py1; e2x = px2 - px1; e2y = py2 - py1;
        c1 = e1x * e2y - e1y * e2x;
        e1x = px1 - px2; e1y = py1 - py2; e2x = px3 - px2; e2y = py3 - py2;
        c2 = e1x * e2y - e1y * e2x;
        e1x = px2 - px3; e1y = py2 - py3; e2x = px0 - px3; e2y = py0 - py3;
        c3 = e1x * e2y - e1y * e2x;
    }
    float sref = (c0 < 0.0f) ? -1.0f : 1.0f;   // sign(c0), 0 -> +1
    float pen = fmaxf(-sref * c0, 0.0f) + fmaxf(-sref * c1, 0.0f)
              + fmaxf(-sref * c2, 0.0f) + fmaxf(-sref * c3, 0.0f);

    loss += CONVEX_WEIGHT * (pen * 0.25f);

    // nt store is safe: d_out is only read back host-side after the replay.
    __builtin_nontemporal_store(loss, &out[b]);
}

extern "C" void kernel_launch(void* const* d_in, const int* in_sizes, int n_in,
                              void* d_out, int out_size, void* d_ws, size_t ws_size,
                              hipStream_t stream)
{
    const float4* pred = (const float4*)d_in[0];
    const float4* targ = (const float4*)d_in[1];
    float* out = (float*)d_out;
    int B = in_sizes[0] / 8;   // (B, 4, 2) floats

    const int threads = 256;
    int blocks = (B + threads - 1) / threads;
    mgiou2dplus_kernel<<<blocks, threads, 0, stream>>>(pred, targ, out, B);
}